// Round 19
// baseline (30.061 us; speedup 1.0000x reference)
//
#include <hip/hip_runtime.h>
#include <hip/hip_bf16.h>

#define NBINS 32
#define CHUNK 128           // voxels per chunk per stream
#define NROWS 34            // rows 1..32 = bins 0..31; rows 0/33 = clamp garbage
#define STR 136             // halfs per row; 272B stride, 16B-aligned rows
#define TILE_HALVES (NROWS * STR)        // 4624 halfs = 9248 B
#define BUF_HALVES (2 * TILE_HALVES)     // A+B pair per stream: 18496 B
#define NTHREADS 512        // 8 waves: group0 = waves 0-3 (stream 0), group1 = waves 4-7
#define NVOX 884736         // 96^3
#define BPB 384             // grid (384,2) = 768 blocks = exactly 3/CU (24 waves/CU, 37 KB LDS)
#define NCH 9               // chunks per stream: 9 * 384 * 2 = 6912 slabs, perfectly uniform
#define NSLOTS 16

typedef __attribute__((ext_vector_type(8))) _Float16 half8;
typedef __attribute__((ext_vector_type(16))) float f32x16;
typedef __attribute__((ext_vector_type(4))) int i32x4;

// Parzen 6-tap window, exp-reduced (R18-validated, 1 exp): w_o ∝ c[o+s]·t^o·t^s,
// t = e^{4u}; common factors cancel in normalization. Same tap set/masking as R4+.
__device__ __forceinline__ void compute_w(float x, int& kb, _Float16* wq) {
    float tt = x * 31.0f;
    float kf = rintf(tt);
    int ki = (int)kf;
    float u = tt - kf;               // [-0.5, 0.5]
    const bool sp = (u > 0.0f);
    kb = ki - 3 + (sp ? 1 : 0);

    float t1 = __expf(4.0f * u);
    float t2 = t1 * t1;
    float t3 = t2 * t1;
    float t4 = t2 * t2;
    float t5 = t3 * t2;
    float ts = sp ? t1 : 1.0f;
    const float c0 = 1.50343918e-8f;   // e^-18
    const float c1 = 3.35462628e-4f;   // e^-8
    const float c2 = 1.35335283e-1f;   // e^-2
    const float c3 = 1.0f;

    float w[6];
    float s = 0.0f;
    {
        float e;
        e = (sp ? c1 : c0) * 1.0f * ts; e = ((unsigned)(kb + 0) < NBINS) ? e : 0.0f; w[0] = e; s += e;
        e = (sp ? c2 : c1) * t1 * ts;   e = ((unsigned)(kb + 1) < NBINS) ? e : 0.0f; w[1] = e; s += e;
        e = (sp ? c3 : c2) * t2 * ts;   e = ((unsigned)(kb + 2) < NBINS) ? e : 0.0f; w[2] = e; s += e;
        e = (sp ? c2 : c3) * t3 * ts;   e = ((unsigned)(kb + 3) < NBINS) ? e : 0.0f; w[3] = e; s += e;
        e = (sp ? c1 : c2) * t4 * ts;   e = ((unsigned)(kb + 4) < NBINS) ? e : 0.0f; w[4] = e; s += e;
        e = (sp ? c0 : c1) * t5 * ts;   e = ((unsigned)(kb + 5) < NBINS) ? e : 0.0f; w[5] = e; s += e;
    }
    float rinv = 1.0f / s;
#pragma unroll
    for (int o = 0; o < 6; ++o) wq[o] = (_Float16)(w[o] * rinv);
}

// Unconditional clamped writes: OOB taps land in garbage rows 0/33 (never read).
__device__ __forceinline__ void zero6(_Float16* __restrict__ L, int col, int kb) {
#pragma unroll
    for (int o = 0; o < 6; ++o) {
        int r = min(max(kb + o, -1), 32) + 1;
        L[r * STR + col] = (_Float16)0.0f;
    }
}
__device__ __forceinline__ void scatter6(_Float16* __restrict__ L, int col, int kb,
                                         const _Float16* wq) {
#pragma unroll
    for (int o = 0; o < 6; ++o) {
        int r = min(max(kb + o, -1), 32) + 1;
        L[r * STR + col] = wq[o];
    }
}

__global__ __launch_bounds__(NTHREADS, 6)   // 6 waves/EU = 3 blocks/CU of 8 waves; VGPR cap 85
void mi_hist_kernel(const float* __restrict__ pred, const float* __restrict__ targ,
                    float* __restrict__ hist /* [NSLOTS][2][32][32] */) {
    // two per-stream buffer pairs: [g][A|B]
    __shared__ __attribute__((aligned(16))) _Float16 smem[2 * BUF_HALVES];   // 36992 B

    const int tid = threadIdx.x;
    const int bx = blockIdx.x;
    const int batch = blockIdx.y;
    const int g = tid >> 8;                        // stream/group: waves 0-3 -> 0, 4-7 -> 1
    const int col = tid & 127;
    const int isB = (tid >> 7) & 1;                // within group: first 128 -> A, next 128 -> B
    const float* src = (isB ? targ : pred) + (size_t)batch * NVOX;
    _Float16* T = smem + g * BUF_HALVES + isB * TILE_HALVES;     // scatter target
    const _Float16* PA = smem + g * BUF_HALVES;                  // MFMA sources (own group)
    const _Float16* PB = PA + TILE_HALVES;

    const int lane = tid & 63;
    const int gwave = (tid >> 6) & 3;
    // mfma_f32_32x32x16_f16: row(col)=lane&31 (bin b -> row b+1), wave owns K [gwave*32,+32)
    const int frag = (1 + (lane & 31)) * STR + gwave * 32 + 8 * (lane >> 5);

    // preload ALL 9 chunk values -> no vmem in the main loop
    float xs[NCH];
#pragma unroll
    for (int c = 0; c < NCH; ++c)
        xs[c] = src[((size_t)(c * (2 * BPB) + bx * 2 + g)) * CHUNK + col];

    // zero both buffer pairs once (2*BUF_HALVES/8 = 2312 b128)
    {
        i32x4 z = {0, 0, 0, 0};
        i32x4* zp = (i32x4*)smem;
#pragma unroll
        for (int i = 0; i < 5; ++i) {
            int idx = i * NTHREADS + tid;
            if (idx < (2 * BUF_HALVES) / 8) zp[idx] = z;
        }
    }

    f32x16 acc;
#pragma unroll
    for (int r = 0; r < 16; ++r) acc[r] = 0.0f;

    int kb_old = 0;
    const bool isG0 = (g == 0);

#define DO_MFMA() { \
        _Pragma("unroll") \
        for (int kk = 0; kk < 2; ++kk) { \
            half8 af = *(const half8*)&PA[frag + kk * 16]; \
            half8 bf = *(const half8*)&PB[frag + kk * 16]; \
            acc = __builtin_amdgcn_mfma_f32_32x32x16_f16(af, bf, acc, 0, 0, 0); \
        } }

    // Phase protocol (20 barriers, 18 chunks/block):
    //   even(c): g0 scatters chunk c   | g1 MFMAs chunk c-1 (+ computes wq(c))
    //   odd(c) : g0 MFMAs chunk c      | g1 scatters chunk c
    // Every phase mixes ds_writes + ds_reads on the LDS pipe; WAR/visibility
    // separated by exactly one barrier in all cases.
#pragma unroll
    for (int c = 0; c <= NCH; ++c) {
        _Float16 wq[6]; int kb = 0;
        if (isG0 && c < NCH) compute_w(xs[c], kb, wq);
        __syncthreads();                           // even(c)
        if (isG0) {
            if (c < NCH) {
                if (c >= 1) zero6(T, col, kb_old);
                scatter6(T, col, kb, wq);
                kb_old = kb;
            }
        } else {
            if (c >= 1) DO_MFMA();                 // g1 chunk c-1
            if (c < NCH) compute_w(xs[c], kb, wq);
        }
        __syncthreads();                           // odd(c)
        if (isG0) {
            if (c < NCH) DO_MFMA();                // g0 chunk c
        } else if (c < NCH) {
            if (c >= 1) zero6(T, col, kb_old);
            scatter6(T, col, kb, wq);
            kb_old = kb;
        }
    }
#undef DO_MFMA

    __syncthreads();                               // all LDS traffic drained before reuse

    // block reduce: 8 waves hold K-split/stream-split partials of the SAME 32x32.
    // C/D layout (32x32): col = lane&31, row = (reg&3) + 8*(reg>>2) + 4*(lane>>5)
    float* red = (float*)smem;                     // 8 * 1024 floats = 32 KB (fits 36.99 KB)
    const int wid = tid >> 6;
    const int colc = lane & 31;
    const int rlo = 4 * (lane >> 5);
#pragma unroll
    for (int r = 0; r < 16; ++r) {
        int rowc = (r & 3) + 8 * (r >> 2) + rlo;
        red[wid * 1024 + rowc * 32 + colc] = acc[r];
    }
    __syncthreads();
    float* H = hist + ((size_t)(bx & (NSLOTS - 1)) * 2 + batch) * 1024;
    for (int idx = tid; idx < 1024; idx += NTHREADS) {
        float s = 0.0f;
#pragma unroll
        for (int w = 0; w < 8; ++w) s += red[w * 1024 + idx];
        atomicAdd(&H[idx], s);
    }
}

__global__ void mi_reduce_kernel(const float* __restrict__ hist, float* __restrict__ out) {
    __shared__ float s_pab[2 * NBINS * NBINS];
    __shared__ double s_pa[2][NBINS];
    __shared__ double s_pb[2][NBINS];
    __shared__ double s_red[1024];
    const int tid = threadIdx.x;
    const double invN = 1.0 / (double)NVOX;

    for (int g = tid; g < 512; g += 1024) {
        float4 s = make_float4(0.f, 0.f, 0.f, 0.f);
        for (int sl = 0; sl < NSLOTS; ++sl) {
            float4 v = ((const float4*)hist)[sl * 512 + g];
            s.x += v.x; s.y += v.y; s.z += v.z; s.w += v.w;
        }
        ((float4*)s_pab)[g] = s;
    }
    __syncthreads();

    if (tid < 64) {
        int b = tid >> 5, i = tid & 31;
        double s = 0.0;
        for (int j = 0; j < NBINS; ++j) s += (double)s_pab[(b * NBINS + i) * NBINS + j];
        s_pa[b][i] = s * invN;
    } else if (tid < 128) {
        int t2 = tid - 64;
        int b = t2 >> 5, j = t2 & 31;
        double s = 0.0;
        for (int i = 0; i < NBINS; ++i) s += (double)s_pab[(b * NBINS + i) * NBINS + j];
        s_pb[b][j] = s * invN;
    }
    __syncthreads();

    double acc = 0.0;
    for (int idx = tid; idx < 2 * NBINS * NBINS; idx += 1024) {
        int b = idx >> 10;
        int cell = idx & 1023;
        int i = cell >> 5, j = cell & 31;
        double pab = (double)s_pab[idx] * invN;
        double papb = s_pa[b][i] * s_pb[b][j];
        acc += pab * log((pab + 1e-7) / (papb + 1e-7) + 1e-7);
    }
    s_red[tid] = acc;
    __syncthreads();
    for (int s2 = 512; s2 > 0; s2 >>= 1) {
        if (tid < s2) s_red[tid] += s_red[tid + s2];
        __syncthreads();
    }
    if (tid == 0) out[0] = (float)(-0.5 * s_red[0]);
}

extern "C" void kernel_launch(void* const* d_in, const int* in_sizes, int n_in,
                              void* d_out, int out_size, void* d_ws, size_t ws_size,
                              hipStream_t stream) {
    const float* pred = (const float*)d_in[0];
    const float* targ = (const float*)d_in[1];
    float* hist = (float*)d_ws;
    float* out = (float*)d_out;

    hipMemsetAsync(hist, 0, NSLOTS * 2 * NBINS * NBINS * sizeof(float), stream);
    dim3 grid(BPB, 2);
    hipLaunchKernelGGL(mi_hist_kernel, grid, dim3(NTHREADS), 0, stream, pred, targ, hist);
    hipLaunchKernelGGL(mi_reduce_kernel, dim3(1), dim3(1024), 0, stream, hist, out);
}